// Round 5
// baseline (164.712 us; speedup 1.0000x reference)
//
#include <hip/hip_runtime.h>
#include <hip/hip_bf16.h>
#include <math.h>

// R14: occupancy at constant amortization (R13 post-mortem: ~25 cyc/issue,
//   all pipes <20% per-SIMD -> latency-bound; R12 proved occupancy without
//   amortization loses; this round raises waves/SIMD while keeping NB=4).
//   - A2f (32 persistent regs) -> per-block LDS "register file", stride-36
//     dwords (banks rotate 4/lane, 16B aligned), re-read per tile with an
//     opaq-pinned base so LICM can't hoist the reads back into registers.
//     Weights are identical across waves -> one 8 KB copy per block.
//   - ci (b2) back to the cw[] LDS broadcast table (R10-proven), freeing 16
//     more persistent regs. cw[128] = b2 | W3.
//   - __launch_bounds__(256,5): 102-reg cap -> 5 waves/SIMD.
//   - pack_weights merged into make_patches (one launch fewer).
//   Carried: NB=4 one-group-per-iter (no deep pipeline), packed weight-frag
//   tables, K=32 layer2 MFMA (slot-permuted), v_cvt_pk_bf16_f32 RNE,
//   pk_fma epilogue with |x| identity, v_fract_f32 gather, patch bilerp.

#define NTHREADS 256
#define NB 4

typedef __attribute__((ext_vector_type(4))) short s16x4;  // 4 bf16 = 2 VGPRs
typedef __attribute__((ext_vector_type(8))) short s16x8;  // 8 bf16 = 4 VGPRs
typedef __attribute__((ext_vector_type(8))) __bf16 bf16x8;
typedef __attribute__((ext_vector_type(4))) float f32x4;
typedef __attribute__((ext_vector_type(2))) float f32x2;
typedef __attribute__((ext_vector_type(4))) int i32x4;
typedef __attribute__((ext_vector_type(2))) int i32x2;

static __device__ __forceinline__ short f2bf(float f) {
    return __builtin_bit_cast(short, __float2bfloat16(f));  // RNE (SW path)
}
static __device__ __forceinline__ int pk2(float lo, float hi) {
    unsigned short l = (unsigned short)f2bf(lo);
    unsigned short h = (unsigned short)f2bf(hi);
    return (int)(((unsigned int)h << 16) | (unsigned int)l);
}
// HW packed bf16 convert, RNE: dst.lo = bf16(a), dst.hi = bf16(b). 1 inst.
static __device__ __forceinline__ int cvt_pk_bf16(float a, float b) {
    int r;
    asm("v_cvt_pk_bf16_f32 %0, %1, %2" : "=v"(r) : "v"(a), "v"(b));
    return r;
}
// VOP3P packed f32 (dual element per issue). Bit-exact vs 2x scalar fmaf/mul.
static __device__ __forceinline__ f32x2 pk_fma(f32x2 a, f32x2 b, f32x2 c) {
    f32x2 d;
    asm("v_pk_fma_f32 %0, %1, %2, %3" : "=v"(d) : "v"(a), "v"(b), "v"(c));
    return d;
}
static __device__ __forceinline__ f32x2 pk_mul(f32x2 a, f32x2 b) {
    f32x2 d;
    asm("v_pk_mul_f32 %0, %1, %2" : "=v"(d) : "v"(a), "v"(b));
    return d;
}
static __device__ __forceinline__ float fractf_hw(float x) {
    float r;
    asm("v_fract_f32 %0, %1" : "=v"(r) : "v"(x));  // x - floor(x), exact
    return r;
}
static __device__ __forceinline__ float bflo(int u) {
    return __builtin_bit_cast(float, u << 16);
}
static __device__ __forceinline__ float bfhi(int u) {
    return __builtin_bit_cast(float, (int)(u & 0xffff0000));
}
// Opacity pin: keeps an index loop-variant so LICM can't hoist LDS reads
// back into live registers.
static __device__ __forceinline__ int opaq(int x) {
    asm volatile("" : "+v"(x));
    return x;
}

// ---- preproc (single launch): patches + per-lane MFMA weight fragments ----
// gid < 131072: patch tables. patch[id=(y0<<8)|x0]: int[8]:
//   [0..2]=(bl<<16)|tl per ch, [3..5]=(br<<16)|tr.
// gid in [131072,131136): pack weight frags:
//   wt1[lane*8  + mt*2 + (j>>1)]          layer1 A frag (4x s16x4 / lane)
//   wt2[lane*32 + (kt2*4+mt)*4 + (j2>>1)] layer2 A frag (8x s16x8 / lane)
__global__ __launch_bounds__(256) void make_patches(
    const float* __restrict__ gP, const float* __restrict__ gD,
    const float* __restrict__ W1, const float* __restrict__ b1,
    const float* __restrict__ W2, int* __restrict__ outP,
    int* __restrict__ outD, int* __restrict__ wt1, int* __restrict__ wt2) {
    int gid = blockIdx.x * 256 + threadIdx.x;
    if (gid < 131072) {
        const float* g = (gid < 65536) ? gP : gD;
        int* po = (gid < 65536) ? outP : outD;
        int id = gid & 65535;
        int y0 = id >> 8, x0 = id & 255;
        int x1 = min(x0 + 1, 255), y1 = min(y0 + 1, 255);
        const float* tl = g + (y0 * 256 + x0) * 3;
        const float* tr = g + (y0 * 256 + x1) * 3;
        const float* bl = g + (y1 * 256 + x0) * 3;
        const float* br = g + (y1 * 256 + x1) * 3;
        i32x4 u0;
        i32x2 u1;
        u0[0] = pk2(tl[0], bl[0]);
        u0[1] = pk2(tl[1], bl[1]);
        u0[2] = pk2(tl[2], bl[2]);
        u0[3] = pk2(tr[0], br[0]);
        u1[0] = pk2(tr[1], br[1]);
        u1[1] = pk2(tr[2], br[2]);
        *(i32x4*)(po + id * 8) = u0;
        *(i32x2*)(po + id * 8 + 4) = u1;
    } else if (gid < 131136) {
        int lane = gid - 131072;  // 0..63
        int c = lane & 15, q = lane >> 4, q4 = q * 4;
#pragma unroll
        for (int mt = 0; mt < 4; ++mt) {
            int f = mt * 16 + c;
            float v[4];
#pragma unroll
            for (int j = 0; j < 4; ++j) {
                int k = q4 + j;
                float x = 0.0f;
                if (k < 6) x = W1[f * 6 + k];
                else if (k == 6) x = b1[f];
                v[j] = x;
            }
            wt1[lane * 8 + mt * 2 + 0] = pk2(v[0], v[1]);
            wt1[lane * 8 + mt * 2 + 1] = pk2(v[2], v[3]);
        }
#pragma unroll
        for (int kt2 = 0; kt2 < 2; ++kt2)
#pragma unroll
            for (int mt = 0; mt < 4; ++mt) {
                int n2 = mt * 16 + c;
                float v[8];
#pragma unroll
                for (int j2 = 0; j2 < 8; ++j2) {
                    int k = kt2 * 32 + ((j2 >> 2) * 16) + q4 + (j2 & 3);
                    v[j2] = W2[n2 * 64 + k];
                }
                int base = lane * 32 + (kt2 * 4 + mt) * 4;
#pragma unroll
                for (int h = 0; h < 4; ++h)
                    wt2[base + h] = pk2(v[2 * h], v[2 * h + 1]);
            }
    }
}

static __device__ __forceinline__ void patch_issue(
    const int* __restrict__ tab, float px, float py, int* P, float& xf,
    float& yf) {
    float fx = px * 255.0f;
    float fy = py * 255.0f;
    int x0 = (int)fx;  // trunc == floor, fx >= 0
    int y0 = (int)fy;
    xf = fractf_hw(fx);  // jnp.mod(fx,1.0), fx >= 0
    yf = fractf_hw(fy);
    int idx = (y0 << 8) | x0;
    i32x4 a = *(const i32x4*)(tab + idx * 8);
    i32x2 b = *(const i32x2*)(tab + idx * 8 + 4);
    P[0] = a[0]; P[1] = a[1]; P[2] = a[2];
    P[3] = a[3]; P[4] = b[0]; P[5] = b[1];
}

static __device__ __forceinline__ void patch_lerp(const int* P, float xf,
                                                  float yf, float* f) {
#pragma unroll
    for (int ch = 0; ch < 3; ++ch) {
        float tl = bflo(P[ch]), bl = bfhi(P[ch]);
        float tr = bflo(P[ch + 3]), br = bfhi(P[ch + 3]);
        float top = fmaf(xf, tr - tl, tl);
        float bot = fmaf(xf, br - bl, bl);
        f[ch] = fmaf(yf, bot - top, top);
    }
}

__global__ __launch_bounds__(NTHREADS, 5) void mlp_mfma_kernel(
    const float* __restrict__ pos, const float* __restrict__ dir,
    const int* __restrict__ patP, const int* __restrict__ patD,
    const int* __restrict__ wt1, const int* __restrict__ wt2,
    const float* __restrict__ b2, const float* __restrict__ W3,
    const float* __restrict__ b3, float* __restrict__ out) {
    __shared__ int lds_F[4 * 64 * 4];        // per-wave feature tile, 4096 B
    __shared__ __align__(16) float cw[128];  // [0:64)=b2, [64:128)=W3
    // layer2 weight frags, swizzled: frag (kt2,mt) of lane l at dword
    // l*36 + (kt2*4+mt)*4  (stride 36 -> banks rotate 4/lane, 16B aligned)
    __shared__ __align__(16) int wt2_lds[64 * 36];  // 9216 B

    const int tid = threadIdx.x;
    if (tid < 128) cw[tid] = (tid < 64) ? b2[tid] : W3[tid - 64];
#pragma unroll
    for (int g = tid; g < 2048; g += 256) {
        int ls = g >> 5, off = g & 31;
        wt2_lds[ls * 36 + off] = wt2[g];
    }
    __syncthreads();

    const int w = tid >> 6;
    const int lane = tid & 63;
    const int c = lane & 15;
    const int q = lane >> 4;
    const int q4 = q * 4;

    int* FB = lds_F + w * (64 * 4);
    const int wb = lane * 36;  // this lane's wt2_lds dword base

    // ---- layer1 weight fragments: straight loads from the packed table ----
    s16x4 A1f[4];
#pragma unroll
    for (int mt = 0; mt < 4; ++mt)
        A1f[mt] = __builtin_bit_cast(
            s16x4, *(const i32x2*)(wt1 + lane * 8 + mt * 2));

    const float b3s = b3[0];
    const int dbias = pk2(1.0f, 0.0f);
    const f32x2 c001 = {0.01f, 0.01f};

    const long wave_global = (long)blockIdx.x * 4 + w;
    const long base0 = wave_global * (64L * NB);
    const float2* pos2 = (const float2*)pos;
    const float2* dir2 = (const float2*)dir;

    // coords for group 0; prefetched each iter for ib+1
    float2 cp = pos2[base0 + lane];
    float2 cd = dir2[base0 + lane];

#pragma unroll 1
    for (int ib = 0; ib < NB; ++ib) {
        const long base = base0 + ib * 64;

        // gather patches for this group
        int P0_[12];
        float fr0[4];
        patch_issue(patP, cp.x, cp.y, P0_, fr0[0], fr0[1]);
        patch_issue(patD, cd.x, cd.y, P0_ + 6, fr0[2], fr0[3]);

        // prefetch coords for next group
        {
            int mb = min(ib + 1, NB - 1);
            cp = pos2[base0 + mb * 64 + lane];
            cd = dir2[base0 + mb * 64 + lane];
        }

        // featurize + pack into this wave's LDS tile (in-order, no barrier)
        {
            float feat[6];
            patch_lerp(P0_, fr0[0], fr0[1], feat);
            patch_lerp(P0_ + 6, fr0[2], fr0[3], feat + 3);
            i32x4 dv;
            dv[0] = cvt_pk_bf16(feat[0], feat[1]);
            dv[1] = cvt_pk_bf16(feat[2], feat[3]);
            dv[2] = cvt_pk_bf16(feat[4], feat[5]);
            dv[3] = dbias;
            *(i32x4*)(FB + lane * 4) = dv;  // row = point
        }

        // ---- 4 tiles of 16 points ----
        float s[4];
#pragma unroll
        for (int t = 0; t < 4; ++t) {
            // feature B-frag: B[k=q*4+j][n=c], point = t*16+c.
            i32x2 bi = *(const i32x2*)(FB + (t * 16 + c) * 4 + (q & 1) * 2);
            s16x4 bfeat = __builtin_bit_cast(s16x4, bi);

            // layer2 A-frags from the LDS register file; opaq pins the base
            // per tile so the reads are NOT hoisted into 32 persistent regs.
            i32x4 A2r[8];
            {
                const int wbo = opaq(wb);
#pragma unroll
                for (int i = 0; i < 8; ++i)
                    A2r[i] = *(const i32x4*)(wt2_lds + wbo + i * 4);
            }

            // layer 1: D1[f][p], 4 f-tiles, one K-tile
            const f32x4 zacc = {0.f, 0.f, 0.f, 0.f};
            f32x4 a1[4];
#pragma unroll
            for (int mt = 0; mt < 4; ++mt)
                a1[mt] = __builtin_amdgcn_mfma_f32_16x16x16bf16_1k(
                    A1f[mt], bfeat, zacc, 0, 0, 0);

            // leaky + HW packed cvt
            i32x4 bbi[2];
#pragma unroll
            for (int kt2 = 0; kt2 < 2; ++kt2)
#pragma unroll
                for (int h = 0; h < 2; ++h) {
                    f32x4 x = a1[kt2 * 2 + h];
                    f32x2 xlo = {x[0], x[1]}, xhi = {x[2], x[3]};
                    f32x2 ylo = pk_mul(xlo, c001);
                    f32x2 yhi = pk_mul(xhi, c001);
                    float l0 = fmaxf(x[0], ylo[0]);
                    float l1 = fmaxf(x[1], ylo[1]);
                    float l2 = fmaxf(x[2], yhi[0]);
                    float l3 = fmaxf(x[3], yhi[1]);
                    bbi[kt2][h * 2 + 0] = cvt_pk_bf16(l0, l1);
                    bbi[kt2][h * 2 + 1] = cvt_pk_bf16(l2, l3);
                }

            // layer 2: D2[n2][p], C init = b2 from LDS broadcast table.
            f32x4 a2[4];
            {
                const float* cwb = cw + opaq(q4);
#pragma unroll
                for (int mt = 0; mt < 4; ++mt)
                    a2[mt] = *(const f32x4*)(cwb + mt * 16);
            }
#pragma unroll
            for (int kt2 = 0; kt2 < 2; ++kt2) {
                bf16x8 bb = __builtin_bit_cast(bf16x8, bbi[kt2]);
#pragma unroll
                for (int mt = 0; mt < 4; ++mt)
                    a2[mt] = __builtin_amdgcn_mfma_f32_16x16x32_bf16(
                        __builtin_bit_cast(bf16x8, A2r[kt2 * 4 + mt]), bb,
                        a2[mt], 0, 0, 0);
            }

            // epilogue: sum leaky(x)*w = 0.505*sum(x*w) + 0.495*sum(|x|*w)
            // via v_pk_fma_f32; |x| = v_and. W3 from LDS broadcast.
            f32x2 tx = {0.f, 0.f}, ta = {0.f, 0.f};
            const float* cww = cw + opaq(64 + q4);
#pragma unroll
            for (int mt = 0; mt < 4; ++mt) {
                const f32x4 wv = *(const f32x4*)(cww + mt * 16);
                f32x2 w0 = {wv[0], wv[1]}, w1 = {wv[2], wv[3]};
                f32x4 x = a2[mt];
                i32x4 xb = __builtin_bit_cast(i32x4, x);
                i32x4 ab = {xb[0] & 0x7fffffff, xb[1] & 0x7fffffff,
                            xb[2] & 0x7fffffff, xb[3] & 0x7fffffff};
                f32x4 xa = __builtin_bit_cast(f32x4, ab);
                f32x2 xlo = {x[0], x[1]}, xhi = {x[2], x[3]};
                f32x2 alo = {xa[0], xa[1]}, ahi = {xa[2], xa[3]};
                tx = pk_fma(xlo, w0, tx);
                tx = pk_fma(xhi, w1, tx);
                ta = pk_fma(alo, w0, ta);
                ta = pk_fma(ahi, w1, ta);
            }
            float tt = fmaf(0.505f, tx[0] + tx[1],
                            0.495f * (ta[0] + ta[1]));
            tt += __shfl_xor(tt, 16, 64);
            tt += __shfl_xor(tt, 32, 64);
            s[t] = tt;  // sum for point t*16 + c, in all quads
        }

        // lane (c,q) emits point q*16 + c with value s[q]
        float sa = (q & 1) ? s[1] : s[0];
        float sb = (q & 1) ? s[3] : s[2];
        float v = (q & 2) ? sb : sa;
        v += b3s;
        v = 1.0f / (1.0f + __expf(-v));
        out[base + q * 16 + c] = v;
    }
}

extern "C" void kernel_launch(void* const* d_in, const int* in_sizes, int n_in,
                              void* d_out, int out_size, void* d_ws,
                              size_t ws_size, hipStream_t stream) {
    const float* pos = (const float*)d_in[0];
    const float* dir = (const float*)d_in[1];
    const float* pos_grid = (const float*)d_in[2];
    const float* dir_grid = (const float*)d_in[3];
    const float* W1 = (const float*)d_in[4];
    const float* b1 = (const float*)d_in[5];
    const float* W2 = (const float*)d_in[6];
    const float* b2 = (const float*)d_in[7];
    const float* W3 = (const float*)d_in[8];
    const float* b3 = (const float*)d_in[9];
    float* out = (float*)d_out;

    int* patP = (int*)d_ws;        // 65536 * 32 B = 2 MB
    int* patD = patP + 65536 * 8;  // 2 MB
    int* wt1 = patD + 65536 * 8;   // 2048 B  (layer1 frags)
    int* wt2 = wt1 + 512;          // 8192 B  (layer2 frags)

    // 513 blocks: 512 for the patch tables + 1 for weight-frag packing
    make_patches<<<513, 256, 0, stream>>>(pos_grid, dir_grid, W1, b1, W2,
                                          patP, patD, wt1, wt2);

    const int n = in_sizes[0] / 2;   // points
    const int batches = n / 64;      // 32768 for N=2M
    const int waves = batches / NB;  // 8192
    const int blocks = waves / 4;    // 2048

    mlp_mfma_kernel<<<blocks, NTHREADS, 0, stream>>>(
        pos, dir, patP, patD, wt1, wt2, b2, W3, b3, out);
}

// Round 6
// 137.527 us; speedup vs baseline: 1.1977x; 1.1977x over previous
//
#include <hip/hip_runtime.h>
#include <hip/hip_bf16.h>
#include <math.h>

// R15 = R13 innards + R9 pipeline skeleton (R14 post-mortem: LDS register
//   file = 2.5e7 bank conflicts + 128 ds_read_b128/wave on the layer2
//   critical path -> reverted; occupancy is NOT the lever, confirmed twice).
//   - Single-depth patch pipeline: patch loads for group ib+1 issue at the
//     TOP of iteration ib, the 16-tile MFMA/VALU block covers their ~400cyc
//     latency, featurize lands at the BOTTOM. Same-wave in-order DS ops
//     make the single FB buffer safe (no ping-pong).
//   - Epilogue and leaky de-pk'd to scalar: the VOP3P inline-asm forced
//     pair-building v_movs ({x[0],x[1]} constructions) that made R13's pk
//     conversion time-neutral; scalar 2-fma |x| identity + scalar max keep
//     the op count with zero mov overhead and scheduler freedom.
//   Carried from R13: NB=4, ci(b2)-in-regs, A2f-in-regs from packed wt
//   tables, W3 LDS broadcast (opaq-pinned), K=32 layer2 MFMA (slot-permuted
//   A2f), v_cvt_pk_bf16_f32 RNE (scalar inputs), v_fract_f32 gather,
//   patch-table bilerp, merged preproc launch, __launch_bounds__(256,4).

#define NTHREADS 256
#define NB 4

typedef __attribute__((ext_vector_type(4))) short s16x4;  // 4 bf16 = 2 VGPRs
typedef __attribute__((ext_vector_type(8))) short s16x8;  // 8 bf16 = 4 VGPRs
typedef __attribute__((ext_vector_type(8))) __bf16 bf16x8;
typedef __attribute__((ext_vector_type(4))) float f32x4;
typedef __attribute__((ext_vector_type(4))) int i32x4;
typedef __attribute__((ext_vector_type(2))) int i32x2;

static __device__ __forceinline__ short f2bf(float f) {
    return __builtin_bit_cast(short, __float2bfloat16(f));  // RNE (SW path)
}
static __device__ __forceinline__ int pk2(float lo, float hi) {
    unsigned short l = (unsigned short)f2bf(lo);
    unsigned short h = (unsigned short)f2bf(hi);
    return (int)(((unsigned int)h << 16) | (unsigned int)l);
}
// HW packed bf16 convert, RNE: dst.lo = bf16(a), dst.hi = bf16(b). 1 inst,
// scalar float inputs (no pair-building movs).
static __device__ __forceinline__ int cvt_pk_bf16(float a, float b) {
    int r;
    asm("v_cvt_pk_bf16_f32 %0, %1, %2" : "=v"(r) : "v"(a), "v"(b));
    return r;
}
static __device__ __forceinline__ float fractf_hw(float x) {
    float r;
    asm("v_fract_f32 %0, %1" : "=v"(r) : "v"(x));  // x - floor(x), exact
    return r;
}
static __device__ __forceinline__ float bflo(int u) {
    return __builtin_bit_cast(float, u << 16);
}
static __device__ __forceinline__ float bfhi(int u) {
    return __builtin_bit_cast(float, (int)(u & 0xffff0000));
}
// Opacity pin: keeps an index loop-variant so LICM can't hoist LDS reads
// back into live registers.
static __device__ __forceinline__ int opaq(int x) {
    asm volatile("" : "+v"(x));
    return x;
}

// ---- preproc (single launch): patches + per-lane MFMA weight fragments ----
// gid < 131072: patch tables. patch[id=(y0<<8)|x0]: int[8]:
//   [0..2]=(bl<<16)|tl per ch, [3..5]=(br<<16)|tr.
// gid in [131072,131136): pack weight frags:
//   wt1[lane*8  + mt*2 + (j>>1)]          layer1 A frag (4x s16x4 / lane)
//   wt2[lane*32 + (kt2*4+mt)*4 + (j2>>1)] layer2 A frag (8x s16x8 / lane)
__global__ __launch_bounds__(256) void make_patches(
    const float* __restrict__ gP, const float* __restrict__ gD,
    const float* __restrict__ W1, const float* __restrict__ b1,
    const float* __restrict__ W2, int* __restrict__ outP,
    int* __restrict__ outD, int* __restrict__ wt1, int* __restrict__ wt2) {
    int gid = blockIdx.x * 256 + threadIdx.x;
    if (gid < 131072) {
        const float* g = (gid < 65536) ? gP : gD;
        int* po = (gid < 65536) ? outP : outD;
        int id = gid & 65535;
        int y0 = id >> 8, x0 = id & 255;
        int x1 = min(x0 + 1, 255), y1 = min(y0 + 1, 255);
        const float* tl = g + (y0 * 256 + x0) * 3;
        const float* tr = g + (y0 * 256 + x1) * 3;
        const float* bl = g + (y1 * 256 + x0) * 3;
        const float* br = g + (y1 * 256 + x1) * 3;
        i32x4 u0;
        i32x2 u1;
        u0[0] = pk2(tl[0], bl[0]);
        u0[1] = pk2(tl[1], bl[1]);
        u0[2] = pk2(tl[2], bl[2]);
        u0[3] = pk2(tr[0], br[0]);
        u1[0] = pk2(tr[1], br[1]);
        u1[1] = pk2(tr[2], br[2]);
        *(i32x4*)(po + id * 8) = u0;
        *(i32x2*)(po + id * 8 + 4) = u1;
    } else if (gid < 131136) {
        int lane = gid - 131072;  // 0..63
        int c = lane & 15, q = lane >> 4, q4 = q * 4;
#pragma unroll
        for (int mt = 0; mt < 4; ++mt) {
            int f = mt * 16 + c;
            float v[4];
#pragma unroll
            for (int j = 0; j < 4; ++j) {
                int k = q4 + j;
                float x = 0.0f;
                if (k < 6) x = W1[f * 6 + k];
                else if (k == 6) x = b1[f];
                v[j] = x;
            }
            wt1[lane * 8 + mt * 2 + 0] = pk2(v[0], v[1]);
            wt1[lane * 8 + mt * 2 + 1] = pk2(v[2], v[3]);
        }
#pragma unroll
        for (int kt2 = 0; kt2 < 2; ++kt2)
#pragma unroll
            for (int mt = 0; mt < 4; ++mt) {
                int n2 = mt * 16 + c;
                float v[8];
#pragma unroll
                for (int j2 = 0; j2 < 8; ++j2) {
                    int k = kt2 * 32 + ((j2 >> 2) * 16) + q4 + (j2 & 3);
                    v[j2] = W2[n2 * 64 + k];
                }
                int base = lane * 32 + (kt2 * 4 + mt) * 4;
#pragma unroll
                for (int h = 0; h < 4; ++h)
                    wt2[base + h] = pk2(v[2 * h], v[2 * h + 1]);
            }
    }
}

static __device__ __forceinline__ void patch_issue(
    const int* __restrict__ tab, float px, float py, int* P, float& xf,
    float& yf) {
    float fx = px * 255.0f;
    float fy = py * 255.0f;
    int x0 = (int)fx;  // trunc == floor, fx >= 0
    int y0 = (int)fy;
    xf = fractf_hw(fx);  // jnp.mod(fx,1.0), fx >= 0
    yf = fractf_hw(fy);
    int idx = (y0 << 8) | x0;
    i32x4 a = *(const i32x4*)(tab + idx * 8);
    i32x2 b = *(const i32x2*)(tab + idx * 8 + 4);
    P[0] = a[0]; P[1] = a[1]; P[2] = a[2];
    P[3] = a[3]; P[4] = b[0]; P[5] = b[1];
}

static __device__ __forceinline__ void patch_lerp(const int* P, float xf,
                                                  float yf, float* f) {
#pragma unroll
    for (int ch = 0; ch < 3; ++ch) {
        float tl = bflo(P[ch]), bl = bfhi(P[ch]);
        float tr = bflo(P[ch + 3]), br = bfhi(P[ch + 3]);
        float top = fmaf(xf, tr - tl, tl);
        float bot = fmaf(xf, br - bl, bl);
        f[ch] = fmaf(yf, bot - top, top);
    }
}

__global__ __launch_bounds__(NTHREADS, 4) void mlp_mfma_kernel(
    const float* __restrict__ pos, const float* __restrict__ dir,
    const int* __restrict__ patP, const int* __restrict__ patD,
    const int* __restrict__ wt1, const int* __restrict__ wt2,
    const float* __restrict__ b2, const float* __restrict__ W3,
    const float* __restrict__ b3, float* __restrict__ out) {
    __shared__ int lds_F[4 * 64 * 4];       // per-wave feature tile, 4096 B
    __shared__ __align__(16) float cw[64];  // W3 broadcast table

    const int tid = threadIdx.x;
    if (tid < 64) cw[tid] = W3[tid];
    __syncthreads();

    const int w = tid >> 6;
    const int lane = tid & 63;
    const int c = lane & 15;
    const int q = lane >> 4;
    const int q4 = q * 4;

    int* FB = lds_F + w * (64 * 4);

    // ---- weight fragments: straight loads from the packed tables ----
    s16x4 A1f[4];
#pragma unroll
    for (int mt = 0; mt < 4; ++mt)
        A1f[mt] = __builtin_bit_cast(
            s16x4, *(const i32x2*)(wt1 + lane * 8 + mt * 2));
    s16x8 A2f[2][4];  // [kt2][mt]
#pragma unroll
    for (int kt2 = 0; kt2 < 2; ++kt2)
#pragma unroll
        for (int mt = 0; mt < 4; ++mt)
            A2f[kt2][mt] = __builtin_bit_cast(
                s16x8,
                *(const i32x4*)(wt2 + lane * 32 + (kt2 * 4 + mt) * 4));
    // layer2 C-init (b2) in registers: n2 = mt*16 + q*4 + r, 16B-aligned.
    f32x4 ci[4];
#pragma unroll
    for (int mt = 0; mt < 4; ++mt)
        ci[mt] = *(const f32x4*)(b2 + mt * 16 + q4);

    const float b3s = b3[0];
    const int dbias = pk2(1.0f, 0.0f);

    const long wave_global = (long)blockIdx.x * 4 + w;
    const long base0 = wave_global * (64L * NB);
    const float2* pos2 = (const float2*)pos;
    const float2* dir2 = (const float2*)dir;

    // ---- prologue: featurize group 0 (serial, once); coords for group 1 ----
    float2 cp1, cd1;  // coords for group ib+1 (consumed at iter top)
    {
        float2 c0p = pos2[base0 + lane], c0d = dir2[base0 + lane];
        cp1 = pos2[base0 + 64 + lane];
        cd1 = dir2[base0 + 64 + lane];
        int P0_[12];
        float fr0[4];
        patch_issue(patP, c0p.x, c0p.y, P0_, fr0[0], fr0[1]);
        patch_issue(patD, c0d.x, c0d.y, P0_ + 6, fr0[2], fr0[3]);
        float feat[6];
        patch_lerp(P0_, fr0[0], fr0[1], feat);
        patch_lerp(P0_ + 6, fr0[2], fr0[3], feat + 3);
        i32x4 dv;
        dv[0] = cvt_pk_bf16(feat[0], feat[1]);
        dv[1] = cvt_pk_bf16(feat[2], feat[3]);
        dv[2] = cvt_pk_bf16(feat[4], feat[5]);
        dv[3] = dbias;
        *(i32x4*)(FB + lane * 4) = dv;  // row = point
    }

#pragma unroll 1
    for (int ib = 0; ib < NB; ++ib) {
        const long base = base0 + ib * 64;

        // phase P: issue patch loads for group ib+1 NOW; the 16-tile block
        // below covers their latency. Consumed at phase F (loop bottom).
        int PB[12];
        float frB[4];
        patch_issue(patP, cp1.x, cp1.y, PB, frB[0], frB[1]);
        patch_issue(patD, cd1.x, cd1.y, PB + 6, frB[2], frB[3]);

        // prefetch coords for group ib+2 (consumed next iter top)
        {
            int mb = min(ib + 2, NB - 1);
            cp1 = pos2[base0 + mb * 64 + lane];
            cd1 = dir2[base0 + mb * 64 + lane];
        }

        // ---- 4 tiles of 16 points (reads FB written last iter) ----
        float s[4];
#pragma unroll
        for (int t = 0; t < 4; ++t) {
            // feature B-frag: B[k=q*4+j][n=c], point = t*16+c.
            i32x2 bi = *(const i32x2*)(FB + (t * 16 + c) * 4 + (q & 1) * 2);
            s16x4 bfeat = __builtin_bit_cast(s16x4, bi);

            // layer 1: D1[f][p], 4 f-tiles, one K-tile
            const f32x4 zacc = {0.f, 0.f, 0.f, 0.f};
            f32x4 a1[4];
#pragma unroll
            for (int mt = 0; mt < 4; ++mt)
                a1[mt] = __builtin_amdgcn_mfma_f32_16x16x16bf16_1k(
                    A1f[mt], bfeat, zacc, 0, 0, 0);

            // leaky (scalar mul+max) + HW packed cvt (scalar inputs)
            i32x4 bbi[2];
#pragma unroll
            for (int kt2 = 0; kt2 < 2; ++kt2)
#pragma unroll
                for (int h = 0; h < 2; ++h) {
                    f32x4 x = a1[kt2 * 2 + h];
                    float l0 = fmaxf(x[0], 0.01f * x[0]);
                    float l1 = fmaxf(x[1], 0.01f * x[1]);
                    float l2 = fmaxf(x[2], 0.01f * x[2]);
                    float l3 = fmaxf(x[3], 0.01f * x[3]);
                    bbi[kt2][h * 2 + 0] = cvt_pk_bf16(l0, l1);
                    bbi[kt2][h * 2 + 1] = cvt_pk_bf16(l2, l3);
                }

            // layer 2: D2[n2][p], C init = b2 (registers)
            f32x4 a2[4];
#pragma unroll
            for (int mt = 0; mt < 4; ++mt) a2[mt] = ci[mt];
#pragma unroll
            for (int kt2 = 0; kt2 < 2; ++kt2) {
                bf16x8 bb = __builtin_bit_cast(bf16x8, bbi[kt2]);
#pragma unroll
                for (int mt = 0; mt < 4; ++mt)
                    a2[mt] = __builtin_amdgcn_mfma_f32_16x16x32_bf16(
                        __builtin_bit_cast(bf16x8, A2f[kt2][mt]), bb, a2[mt],
                        0, 0, 0);
            }

            // epilogue: sum leaky(x)*w = 0.505*sum(x*w) + 0.495*sum(|x|*w),
            // scalar 2-chain fma (|x| via v_and); W3 from LDS broadcast.
            float tx = 0.0f, ta = 0.0f;
            const float* cww = cw + opaq(q4);
#pragma unroll
            for (int mt = 0; mt < 4; ++mt) {
                const f32x4 wv = *(const f32x4*)(cww + mt * 16);
#pragma unroll
                for (int r = 0; r < 4; ++r) {
                    float x = a2[mt][r];
                    tx = fmaf(x, wv[r], tx);
                    ta = fmaf(__builtin_fabsf(x), wv[r], ta);
                }
            }
            float tt = fmaf(0.505f, tx, 0.495f * ta);
            tt += __shfl_xor(tt, 16, 64);
            tt += __shfl_xor(tt, 32, 64);
            s[t] = tt;  // sum for point t*16 + c, in all quads
        }

        // lane (c,q) emits point q*16 + c with value s[q]
        float sa = (q & 1) ? s[1] : s[0];
        float sb = (q & 1) ? s[3] : s[2];
        float v = (q & 2) ? sb : sa;
        v += b3s;
        v = 1.0f / (1.0f + __expf(-v));
        out[base + q * 16 + c] = v;

        // phase F: featurize group ib+1 (patch loads issued at iter top).
        // Same-wave in-order DS ops: overwriting FB after the tile reads
        // above is safe without a barrier.
        if (ib + 1 < NB) {
            float feat[6];
            patch_lerp(PB, frB[0], frB[1], feat);
            patch_lerp(PB + 6, frB[2], frB[3], feat + 3);
            i32x4 dv;
            dv[0] = cvt_pk_bf16(feat[0], feat[1]);
            dv[1] = cvt_pk_bf16(feat[2], feat[3]);
            dv[2] = cvt_pk_bf16(feat[4], feat[5]);
            dv[3] = dbias;
            *(i32x4*)(FB + lane * 4) = dv;
        }
    }
}

extern "C" void kernel_launch(void* const* d_in, const int* in_sizes, int n_in,
                              void* d_out, int out_size, void* d_ws,
                              size_t ws_size, hipStream_t stream) {
    const float* pos = (const float*)d_in[0];
    const float* dir = (const float*)d_in[1];
    const float* pos_grid = (const float*)d_in[2];
    const float* dir_grid = (const float*)d_in[3];
    const float* W1 = (const float*)d_in[4];
    const float* b1 = (const float*)d_in[5];
    const float* W2 = (const float*)d_in[6];
    const float* b2 = (const float*)d_in[7];
    const float* W3 = (const float*)d_in[8];
    const float* b3 = (const float*)d_in[9];
    float* out = (float*)d_out;

    int* patP = (int*)d_ws;        // 65536 * 32 B = 2 MB
    int* patD = patP + 65536 * 8;  // 2 MB
    int* wt1 = patD + 65536 * 8;   // 2048 B  (layer1 frags)
    int* wt2 = wt1 + 512;          // 8192 B  (layer2 frags)

    // 513 blocks: 512 for the patch tables + 1 for weight-frag packing
    make_patches<<<513, 256, 0, stream>>>(pos_grid, dir_grid, W1, b1, W2,
                                          patP, patD, wt1, wt2);

    const int n = in_sizes[0] / 2;   // points
    const int batches = n / 64;      // 32768 for N=2M
    const int waves = batches / NB;  // 8192
    const int blocks = waves / 4;    // 2048

    mlp_mfma_kernel<<<blocks, NTHREADS, 0, stream>>>(
        pos, dir, patP, patD, wt1, wt2, b2, W3, b3, out);
}